// Round 12
// baseline (275.120 us; speedup 1.0000x reference)
//
#include <hip/hip_runtime.h>
#include <hip/hip_bf16.h>

typedef unsigned int uint;
typedef unsigned short ushort;
typedef __attribute__((ext_vector_type(8))) short bf16x8;
typedef __attribute__((ext_vector_type(4))) float f32x4;
typedef __attribute__((ext_vector_type(2))) float f32x2;

#define Tn 128
#define Bn 16
#define HH 128
#define G3 384
#define DIN 1024
#define PAD 136   // ushort row stride (272 B, 16B-aligned, breaks pow2 banks)
#define SQP 132   // SQ row stride in floats
#define ABP 132   // ABF row stride in floats

#if __has_builtin(__builtin_amdgcn_cvt_pk_bf16_f32)
__device__ __forceinline__ uint pack2(float a, float b){
    auto v = __builtin_amdgcn_cvt_pk_bf16_f32(a, b);   // lo = a, hi = b, RNE
    union { decltype(v) v2; uint u; } c; c.v2 = v;
    return c.u;
}
#else
__device__ __forceinline__ ushort f2bf_(float f){
    union{float f; uint u;} c; c.f = f;
    uint u = c.u + 0x7fffu + ((c.u >> 16) & 1u);
    return (ushort)(u >> 16);
}
__device__ __forceinline__ uint pack2(float a, float b){
    return ((uint)f2bf_(b) << 16) | (uint)f2bf_(a);
}
#endif
__device__ __forceinline__ ushort f2bf(float f){ return (ushort)(pack2(f, f) & 0xffffu); }

#if __has_builtin(__builtin_amdgcn_fmed3f)
__device__ __forceinline__ float clampf(float x, float lo, float hi){
    return __builtin_amdgcn_fmed3f(x, lo, hi);
}
#else
__device__ __forceinline__ float clampf(float x, float lo, float hi){
    return fminf(hi, fmaxf(lo, x));
}
#endif

__device__ __forceinline__ float rcpf(float x){ return __builtin_amdgcn_rcpf(x); }
__device__ __forceinline__ f32x2 clamp2(f32x2 x, float lo, float hi){
    f32x2 r; r.x = clampf(x.x, lo, hi); r.y = clampf(x.y, lo, hi); return r;
}
__device__ __forceinline__ f32x2 rcp2(f32x2 x){
    f32x2 r; r.x = rcpf(x.x); r.y = rcpf(x.y); return r;
}
// Padé(7,6) tanh on a pair (packed fp32 math)
__device__ __forceinline__ f32x2 tanh2(f32x2 x){
    x = clamp2(x, -5.f, 5.f);
    f32x2 t = x*x;
    f32x2 n = x*(t*(t*(t + 378.f) + 17325.f) + 135135.f);
    f32x2 d = t*(t*(t*28.f + 3150.f) + 62370.f) + 135135.f;
    return n * rcp2(d);
}
__device__ __forceinline__ float tanh_rat(float x){
    x = clampf(x, -5.f, 5.f);
    float t = x*x;
    float n = x*fmaf(t, fmaf(t, (t + 378.f), 17325.f), 135135.f);
    float d = fmaf(t, fmaf(t, fmaf(t, 28.f, 3150.f), 62370.f), 135135.f);
    return n * rcpf(d);
}

// LDS-only barrier: leaves global prefetches (vmcnt) in flight.
__device__ __forceinline__ void bar_lds(){
    asm volatile("s_waitcnt lgkmcnt(0)\n\ts_barrier" ::: "memory");
}

// ============ one-time fp32 -> bf16 weight conversion: Wemb | Wiha | Wihb
__global__ __launch_bounds__(256) void k_cvt(const float* __restrict__ wemb,
                                             const float* __restrict__ wiha,
                                             const float* __restrict__ wihb,
                                             ushort* __restrict__ dst){
    int idx = (blockIdx.x*256 + threadIdx.x)*8;
    const float* s; int off;
    if (idx < 131072){ s = wemb; off = idx; }
    else if (idx < 180224){ s = wiha; off = idx - 131072; }
    else { s = wihb; off = idx - 180224; }
    float4 f0 = *(const float4*)(s + off);
    float4 f1 = *(const float4*)(s + off + 4);
    *(uint4*)(dst + idx) = (uint4){pack2(f0.x,f0.y),pack2(f0.z,f0.w),
                                   pack2(f1.x,f1.y),pack2(f1.z,f1.w)};
}

// ============ fused emb + Gi + WoE (R11 version, unchanged).
__device__ __forceinline__ const uint4* stage_src(int c, const ushort* WembB,
                                                  const ushort* WihaB,
                                                  const ushort* WihbB,
                                                  int wr2, int wc2){
    if (c < 8)  return (const uint4*)(WembB + (size_t)wr2*DIN + c*128 + wc2);
    if (c < 11) return (const uint4*)(WihaB + (size_t)((c-8)*128 + wr2)*HH + wc2);
    return (const uint4*)(WihbB + (size_t)((c-11)*128 + wr2)*HH + wc2);
}

__global__ __launch_bounds__(512) void k_embgi(
    const float* __restrict__ x,      const ushort* __restrict__ WembB,
    const ushort* __restrict__ WihaB, const ushort* __restrict__ WihbB,
    const float* __restrict__ biha,   const float* __restrict__ bhha,
    const float* __restrict__ bihb,   const float* __restrict__ bhhb,
    const float* __restrict__ Wo,
    float* __restrict__ gia, float* __restrict__ gib, float* __restrict__ woE)
{
    __shared__ __align__(16) ushort LX[2][16*PAD];
    __shared__ __align__(16) ushort LW[2][128*PAD];
    __shared__ __align__(16) ushort LE[16*PAD];
    int tid = threadIdx.x;
    int lane = tid & 63, wave = tid >> 6;
    int quad = lane >> 4, n = lane & 15;
    int R0 = blockIdx.x * 8;
    int xr = tid >> 6, xc = (tid & 63) * 2;
    int wr2 = tid >> 2, wc2 = (tid & 3) * 32;

    for (int z = tid; z < 544; z += 512){
        ((uint*)&LX[0][8*PAD])[z] = 0;
        ((uint*)&LX[1][8*PAD])[z] = 0;
        ((uint*)&LE[8*PAD])[z]    = 0;
    }
    {
        const uint4* s0 = stage_src(0, WembB, WihaB, WihbB, wr2, wc2);
        uint4 a0=s0[0], a1=s0[1], a2=s0[2], a3=s0[3];
        float2 v = *(const float2*)(x + (size_t)(R0 + xr)*DIN + xc);
        uint4* d = (uint4*)&LW[0][wr2*PAD + wc2];
        d[0]=a0; d[1]=a1; d[2]=a2; d[3]=a3;
        *(uint*)&LX[0][xr*PAD + xc] = pack2(v.x, v.y);
    }

    f32x4 acc = {0.f,0.f,0.f,0.f};
    for (int c = 0; c < 8; ++c){
        bar_lds();
        int cur = c & 1, nxt = cur ^ 1;
        const uint4* sn = stage_src(c+1, WembB, WihaB, WihbB, wr2, wc2);
        uint4 r0=sn[0], r1=sn[1], r2=sn[2], r3=sn[3];
        float2 vx = {0.f,0.f};
        if (c+1 < 8) vx = *(const float2*)(x + (size_t)(R0 + xr)*DIN + (c+1)*128 + xc);
#pragma unroll
        for (int kb = 0; kb < 4; ++kb){
            bf16x8 a = *(const bf16x8*)&LX[cur][n*PAD + kb*32 + quad*8];
            bf16x8 b = *(const bf16x8*)&LW[cur][(wave*16 + n)*PAD + kb*32 + quad*8];
            acc = __builtin_amdgcn_mfma_f32_16x16x32_bf16(a, b, acc, 0,0,0);
        }
        {
            uint4* d = (uint4*)&LW[nxt][wr2*PAD + wc2];
            d[0]=r0; d[1]=r1; d[2]=r2; d[3]=r3;
            if (c+1 < 8) *(uint*)&LX[nxt][xr*PAD + xc] = pack2(vx.x, vx.y);
        }
    }
    if (quad < 2){
        int e = wave*16 + n;
        float wo = Wo[e];
#pragma unroll
        for (int l = 0; l < 4; ++l){
            int m = quad*4 + l;
            LE[m*PAD + e] = f2bf(acc[l]);
            int row = R0 + m, b_ = row >> 7, pos = row & 127;
            woE[((size_t)(pos*Bn + b_))*HH + e] = wo * acc[l];
        }
    }
    for (int c = 8; c < 14; ++c){
        bar_lds();
        int cur = c & 1, nxt = cur ^ 1;
        uint4 r0, r1, r2, r3;
        if (c < 13){
            const uint4* sn = stage_src(c+1, WembB, WihaB, WihbB, wr2, wc2);
            r0=sn[0]; r1=sn[1]; r2=sn[2]; r3=sn[3];
        }
        f32x4 gc = {0.f,0.f,0.f,0.f};
#pragma unroll
        for (int kb = 0; kb < 4; ++kb){
            bf16x8 a = *(const bf16x8*)&LE[n*PAD + kb*32 + quad*8];
            bf16x8 b = *(const bf16x8*)&LW[cur][(wave*16 + n)*PAD + kb*32 + quad*8];
            gc = __builtin_amdgcn_mfma_f32_16x16x32_bf16(a, b, gc, 0,0,0);
        }
        int nc = c - 8;
        int gband = (nc < 3) ? nc : nc - 3;
        int g = gband*128 + wave*16 + n;
        const float* bi = (nc < 3) ? biha : bihb;
        const float* bh = (nc < 3) ? bhha : bhhb;
        float bias = bi[g] + ((gband < 2) ? bh[g] : 0.f);
        float scale = (gband < 2) ? 0.5f : 1.f;
        float* dst = (nc < 3) ? gia : gib;
        int P = (3*wave + gband)*16 + n;
        if (quad < 2){
#pragma unroll
            for (int l = 0; l < 4; ++l){
                int row = R0 + quad*4 + l, b_ = row >> 7, pos = row & 127;
                dst[((size_t)(pos*Bn + b_))*G3 + P] = scale*(gc[l] + bias);
            }
        }
        if (c < 13){
            uint4* d = (uint4*)&LW[nxt][wr2*PAD + wc2];
            d[0]=r0; d[1]=r1; d[2]=r2; d[3]=r3;
        }
    }
}

// ============ GRU recurrence, 1024 threads.
// G-waves 0-7: 3 Gh tiles + (GT1: Pb tile u | GT0 wave0: 0.5*Wa row) + packed-fp32 gates.
//   GT1 G-waves write raw Pb C-frags (fp32) to ABF — P-waves no longer read HF.
// P-waves 8-15 (GT1): wbeta from ABF (16B read) -> BF; wave 8: q-MFMA over BF.
// Pipeline: step k computes h_k, ABF<-Pb(h_{k-1}), BF<-wbeta_{k-2}, SQ<-q_{k-3}.
template<int GT>
__device__ __forceinline__ void gru_body(
    const float* __restrict__ Whh, const float* __restrict__ bhh,
    const float* __restrict__ Wsc, const float* __restrict__ bsc,
    const float* __restrict__ Gi,  const float* __restrict__ WoE,
    float* __restrict__ outW, int i)
{
    __shared__ __align__(16) ushort HF[2][2048];     // h in B-frag order, dbuf
    __shared__ __align__(16) ushort BFm[2][2048];    // wbeta B-frag, dbuf (GT1)
    __shared__ __align__(16) float ABF[2][16][ABP];  // raw Pb C [chain][row], dbuf (GT1)
    __shared__ __align__(16) float SQ[16][SQP];      // [chain][k] s or q
    int tid = threadIdx.x;
    int lane = tid & 63, wave = tid >> 6;
    int quad = lane >> 4, n = lane & 15;

    if (tid < 256) ((uint4*)HF[1])[tid] = (uint4){0,0,0,0};

    if (wave < 8){
        // ================= G-waves =================
        int u = wave, jb = u*16 + quad*4;
        bf16x8 afr[4][4];
#pragma unroll
        for (int g = 0; g < 3; ++g){
            const float* src = Whh + (size_t)(g*HH + u*16 + n)*HH;
            float s = (g < 2) ? 0.5f : 1.0f;   // fold 0.5 into r,z rows
#pragma unroll
            for (int kb = 0; kb < 4; ++kb){
                const float* p = src + kb*32 + quad*8;
                float4 a = *(const float4*)p, b2 = *(const float4*)(p+4);
                union { uint4 q; bf16x8 v; } cv;
                cv.q.x = pack2(s*a.x, s*a.y);  cv.q.y = pack2(s*a.z, s*a.w);
                cv.q.z = pack2(s*b2.x,s*b2.y); cv.q.w = pack2(s*b2.z,s*b2.w);
                afr[g][kb] = cv.v;
            }
        }
        // 4th tile: GT1 = 0.5*Wb rows (u*16+n); GT0 wave0 = 0.5*Wa in A-row 0
#pragma unroll
        for (int kb = 0; kb < 4; ++kb){
            union { uint4 q; bf16x8 v; } cv;
            cv.q = (uint4){0,0,0,0};
            if (GT){
                const float* p = Wsc + (size_t)(u*16 + n)*HH + kb*32 + quad*8;
                float4 a = *(const float4*)p, b2 = *(const float4*)(p+4);
                cv.q.x = pack2(0.5f*a.x, 0.5f*a.y);  cv.q.y = pack2(0.5f*a.z, 0.5f*a.w);
                cv.q.z = pack2(0.5f*b2.x,0.5f*b2.y); cv.q.w = pack2(0.5f*b2.z,0.5f*b2.w);
            } else if (u == 0 && n == 0){
                const float* p = Wsc + kb*32 + quad*8;
                float4 a = *(const float4*)p, b2 = *(const float4*)(p+4);
                cv.q.x = pack2(0.5f*a.x, 0.5f*a.y);  cv.q.y = pack2(0.5f*a.z, 0.5f*a.w);
                cv.q.z = pack2(0.5f*b2.x,0.5f*b2.y); cv.q.w = pack2(0.5f*b2.z,0.5f*b2.w);
            }
            afr[3][kb] = cv.v;
        }
        f32x2 bh2p[2];
        bh2p[0] = (f32x2){bhh[2*HH + jb], bhh[2*HH + jb + 1]};
        bh2p[1] = (f32x2){bhh[2*HH + jb + 2], bhh[2*HH + jb + 3]};
        float bav = GT ? 0.f : bsc[0];
        f32x2 h0 = {0.f,0.f}, h1 = {0.f,0.f};

        const float* gp = Gi + ((size_t)(i*Bn + n))*G3 + u*48 + quad*4;
        float4 pg0 = *(const float4*)(gp);
        float4 pg1 = *(const float4*)(gp + 16);
        float4 pg2 = *(const float4*)(gp + 32);
        bar_lds();

        for (int k = 0; k <= i; ++k){
            int pos = i - k;
            float4 g0 = pg0, g1 = pg1, g2 = pg2;
            int pnext = (pos > 0) ? pos - 1 : 0;
            const float* gp2 = Gi + ((size_t)(pnext*Bn + n))*G3 + u*48 + quad*4;
            pg0 = *(const float4*)(gp2);
            pg1 = *(const float4*)(gp2 + 16);
            pg2 = *(const float4*)(gp2 + 32);

            const ushort* HR = HF[(k+1)&1];
            f32x4 a0={0.f,0.f,0.f,0.f}, a1=a0, a2=a0, a3=a0;
#pragma unroll
            for (int kb = 0; kb < 4; ++kb){
                bf16x8 bfr = *(const bf16x8*)&HR[(64*kb + lane)*8];
                a0 = __builtin_amdgcn_mfma_f32_16x16x32_bf16(afr[0][kb], bfr, a0, 0,0,0);
                a1 = __builtin_amdgcn_mfma_f32_16x16x32_bf16(afr[1][kb], bfr, a1, 0,0,0);
                a2 = __builtin_amdgcn_mfma_f32_16x16x32_bf16(afr[2][kb], bfr, a2, 0,0,0);
                if (GT || u == 0)
                    a3 = __builtin_amdgcn_mfma_f32_16x16x32_bf16(afr[3][kb], bfr, a3, 0,0,0);
            }
            if (GT){   // stash raw Pb(h_{k-1}) for P-waves
                *(f32x4*)&ABF[(k+1)&1][n][jb] = a3;
            } else if (u == 0 && k >= 1 && lane < 16){
                SQ[lane][k-1] = a3[0] + bav;    // s_{k-1} from C row 0
            }
            // ---- packed gates (2 dims per f32x2)
#pragma unroll
            for (int p2 = 0; p2 < 2; ++p2){
                f32x2 gi0 = p2 ? (f32x2){g0.z,g0.w} : (f32x2){g0.x,g0.y};
                f32x2 gi1 = p2 ? (f32x2){g1.z,g1.w} : (f32x2){g1.x,g1.y};
                f32x2 gi2 = p2 ? (f32x2){g2.z,g2.w} : (f32x2){g2.x,g2.y};
                f32x2 a0p = p2 ? (f32x2){a0[2],a0[3]} : (f32x2){a0[0],a0[1]};
                f32x2 a1p = p2 ? (f32x2){a1[2],a1[3]} : (f32x2){a1[0],a1[1]};
                f32x2 a2p = p2 ? (f32x2){a2[2],a2[3]} : (f32x2){a2[0],a2[1]};
                f32x2 mr = clamp2(gi0 + a0p, -4.f, 4.f);
                f32x2 mz = clamp2(gi1 + a1p, -4.f, 4.f);
                f32x2 tr = mr*mr, tz = mz*mz;
                f32x2 nr = mr*(tr*(tr*(tr*0.5f + 189.f) + 8662.5f) + 67567.5f);
                f32x2 nz = mz*(tz*(tz*(tz*0.5f + 189.f) + 8662.5f) + 67567.5f);
                f32x2 dr = tr*(tr*(tr*28.f + 3150.f) + 62370.f) + 135135.f;
                f32x2 dz = tz*(tz*(tz*28.f + 3150.f) + 62370.f) + 135135.f;
                f32x2 rD = rcp2(dr*dz);
                f32x2 r = nr*dz*rD + 0.5f;
                f32x2 z = nz*dr*rD + 0.5f;
                f32x2 nn = tanh2(gi2 + r*(a2p + bh2p[p2]));
                if (p2 == 0) h0 = nn + z*(h0 - nn);
                else         h1 = nn + z*(h1 - nn);
            }
            *(uint2*)&HF[k&1][((jb>>3)*16 + n)*8 + (jb&4)] =
                (uint2){pack2(h0.x,h0.y), pack2(h1.x,h1.y)};
            bar_lds();
        }
        // ---- tails T1..T3 (barrier schedule shared by all waves)
        {   // T1: Pb(h_i) (GT1) | s_i (GT0 wave0)
            const ushort* HR = HF[i&1];
            if (GT || u == 0){
                f32x4 a3 = {0.f,0.f,0.f,0.f};
#pragma unroll
                for (int kb = 0; kb < 4; ++kb){
                    bf16x8 bfr = *(const bf16x8*)&HR[(64*kb + lane)*8];
                    a3 = __builtin_amdgcn_mfma_f32_16x16x32_bf16(afr[3][kb], bfr, a3, 0,0,0);
                }
                if (GT) *(f32x4*)&ABF[i&1][n][jb] = a3;
                else if (lane < 16) SQ[lane][i] = a3[0] + bav;
            }
            bar_lds();
        }
        bar_lds();   // T2
        bar_lds();   // T3
    } else {
        // ================= P-waves =================
        int u2 = wave - 8, jb = u2*16 + quad*4;
        if (GT){
            bf16x8 onesf;
            {
                union { uint4 q; bf16x8 v; } c1;
                uint o = (n == 0) ? 0x3F803F80u : 0u;
                c1.q = (uint4){o,o,o,o};
                onesf = c1.v;
            }
            f32x2 bb0 = {bsc[jb], bsc[jb+1]}, bb1 = {bsc[jb+2], bsc[jb+3]};
            float4 woA = {0,0,0,0}, woB = {0,0,0,0}, woC = {0,0,0,0};
            bar_lds();

            for (int k = 0; k <= i; ++k){
                woA = woB; woB = woC;
                woC = *(const float4*)(WoE + ((size_t)((i-k)*Bn + n))*HH + jb);
                if (u2 == 0 && k >= 3){   // q_{k-3} = ones . BF[(k+1)&1]
                    const ushort* BR = BFm[(k+1)&1];
                    f32x4 qa = {0.f,0.f,0.f,0.f};
#pragma unroll
                    for (int kb = 0; kb < 4; ++kb){
                        bf16x8 bq = *(const bf16x8*)&BR[(64*kb + lane)*8];
                        qa = __builtin_amdgcn_mfma_f32_16x16x32_bf16(onesf, bq, qa, 0,0,0);
                    }
                    if (lane < 16) SQ[lane][k-3] = qa[0];
                }
                if (k >= 2){   // wbeta_{k-2} from ABF[k&1] (=Pb(h_{k-2})), WoE[i-k+2]=woA
                    f32x4 pb = *(const f32x4*)&ABF[k&1][n][jb];
                    f32x2 w0 = tanh2((f32x2){pb[0],pb[1]} + bb0) * (f32x2){woA.x,woA.y};
                    f32x2 w1 = tanh2((f32x2){pb[2],pb[3]} + bb1) * (f32x2){woA.z,woA.w};
                    *(uint2*)&BFm[k&1][((jb>>3)*16 + n)*8 + (jb&4)] =
                        (uint2){pack2(w0.x,w0.y), pack2(w1.x,w1.y)};
                }
                bar_lds();
            }
            {   // T1: wbeta_{i-1} from ABF[(i+1)&1], WoE[1]=woB; q_{i-2}
                if (i >= 1){
                    f32x4 pb = *(const f32x4*)&ABF[(i+1)&1][n][jb];
                    f32x2 w0 = tanh2((f32x2){pb[0],pb[1]} + bb0) * (f32x2){woB.x,woB.y};
                    f32x2 w1 = tanh2((f32x2){pb[2],pb[3]} + bb1) * (f32x2){woB.z,woB.w};
                    *(uint2*)&BFm[(i+1)&1][((jb>>3)*16 + n)*8 + (jb&4)] =
                        (uint2){pack2(w0.x,w0.y), pack2(w1.x,w1.y)};
                }
                if (u2 == 0 && i >= 2){
                    const ushort* BR = BFm[i&1];
                    f32x4 qa = {0.f,0.f,0.f,0.f};
#pragma unroll
                    for (int kb = 0; kb < 4; ++kb){
                        bf16x8 bq = *(const bf16x8*)&BR[(64*kb + lane)*8];
                        qa = __builtin_amdgcn_mfma_f32_16x16x32_bf16(onesf, bq, qa, 0,0,0);
                    }
                    if (lane < 16) SQ[lane][i-2] = qa[0];
                }
                bar_lds();
            }
            {   // T2: wbeta_i from ABF[i&1], WoE[0]=woC; q_{i-1}
                f32x4 pb = *(const f32x4*)&ABF[i&1][n][jb];
                f32x2 w0 = tanh2((f32x2){pb[0],pb[1]} + bb0) * (f32x2){woC.x,woC.y};
                f32x2 w1 = tanh2((f32x2){pb[2],pb[3]} + bb1) * (f32x2){woC.z,woC.w};
                *(uint2*)&BFm[i&1][((jb>>3)*16 + n)*8 + (jb&4)] =
                    (uint2){pack2(w0.x,w0.y), pack2(w1.x,w1.y)};
                if (u2 == 0 && i >= 1){
                    const ushort* BR = BFm[(i+1)&1];
                    f32x4 qa = {0.f,0.f,0.f,0.f};
#pragma unroll
                    for (int kb = 0; kb < 4; ++kb){
                        bf16x8 bq = *(const bf16x8*)&BR[(64*kb + lane)*8];
                        qa = __builtin_amdgcn_mfma_f32_16x16x32_bf16(onesf, bq, qa, 0,0,0);
                    }
                    if (lane < 16) SQ[lane][i-1] = qa[0];
                }
                bar_lds();
            }
            {   // T3: q_i from BF[i&1]
                if (u2 == 0){
                    const ushort* BR = BFm[i&1];
                    f32x4 qa = {0.f,0.f,0.f,0.f};
#pragma unroll
                    for (int kb = 0; kb < 4; ++kb){
                        bf16x8 bq = *(const bf16x8*)&BR[(64*kb + lane)*8];
                        qa = __builtin_amdgcn_mfma_f32_16x16x32_bf16(onesf, bq, qa, 0,0,0);
                    }
                    if (lane < 16) SQ[lane][i] = qa[0];
                }
                bar_lds();
            }
        } else {
            // GT0 P-waves: barrier companions only
            bar_lds();
            for (int k = 0; k <= i; ++k) bar_lds();
            bar_lds(); bar_lds(); bar_lds();
        }
    }
    if (tid < 512){   // flush SQ -> global, coalesced float4 (k_out masks k > i)
        int cn = tid >> 5, k4 = (tid & 31) * 4;
        *(float4*)&outW[((size_t)(cn*Tn + i))*Tn + k4] = *(const float4*)&SQ[cn][k4];
    }
}

// grid = 256 linear; gt = blk & 1 so each XCD (id%8) hosts only one GRU type.
__global__ __launch_bounds__(1024, 1) void k_gru(
    const float* __restrict__ WhhA, const float* __restrict__ bhhA,
    const float* __restrict__ Wa,   const float* __restrict__ ba,
    const float* __restrict__ WhhB, const float* __restrict__ bhhB,
    const float* __restrict__ Wb,   const float* __restrict__ bb,
    const float* __restrict__ GiA,  const float* __restrict__ GiB,
    const float* __restrict__ WoE,
    float* __restrict__ sW, float* __restrict__ qW)
{
    int i = Tn - 1 - (blockIdx.x >> 1);
    if ((blockIdx.x & 1) == 0) gru_body<0>(WhhA, bhhA, Wa, ba, GiA, nullptr, sW, i);
    else                       gru_body<1>(WhhB, bhhB, Wb, bb, GiB, WoE,    qW, i);
}

// ============ softmax(s) . q per row; one wave per (b,i)
__global__ __launch_bounds__(256) void k_out(const float* __restrict__ sW,
                                             const float* __restrict__ qW,
                                             const float* __restrict__ bo,
                                             float* __restrict__ out){
    int tid = threadIdx.x, lane = tid & 63, w = tid >> 6;
    int r = blockIdx.x*4 + w;
    int i = r & (Tn-1);
    const float* s = sW + (size_t)r*Tn;
    const float* q = qW + (size_t)r*Tn;
    float s0 = (lane     <= i) ? s[lane]      : -1e30f;
    float s1 = (64+lane  <= i) ? s[64+lane]   : -1e30f;
    float m = fmaxf(s0, s1);
#pragma unroll
    for (int off = 32; off; off >>= 1) m = fmaxf(m, __shfl_xor(m, off));
    float e0 = __expf(s0 - m), e1 = __expf(s1 - m);
    float q0 = (lane    <= i) ? q[lane]    : 0.f;
    float q1 = (64+lane <= i) ? q[64+lane] : 0.f;
    float num = e0*q0 + e1*q1, den = e0 + e1;
#pragma unroll
    for (int off = 32; off; off >>= 1){
        num += __shfl_xor(num, off);
        den += __shfl_xor(den, off);
    }
    if (lane == 0) out[r] = num/den + bo[0];
}

extern "C" void kernel_launch(void* const* d_in, const int* in_sizes, int n_in,
                              void* d_out, int out_size, void* d_ws, size_t ws_size,
                              hipStream_t stream) {
    const float* x     = (const float*)d_in[0];
    const float* Wemb  = (const float*)d_in[1];
    const float* Wih_a = (const float*)d_in[2];
    const float* Whh_a = (const float*)d_in[3];
    const float* bih_a = (const float*)d_in[4];
    const float* bhh_a = (const float*)d_in[5];
    const float* Wa    = (const float*)d_in[6];
    const float* ba    = (const float*)d_in[7];
    const float* Wih_b = (const float*)d_in[8];
    const float* Whh_b = (const float*)d_in[9];
    const float* bih_b = (const float*)d_in[10];
    const float* bhh_b = (const float*)d_in[11];
    const float* Wb    = (const float*)d_in[12];
    const float* bb    = (const float*)d_in[13];
    const float* Wo    = (const float*)d_in[14];
    const float* bo    = (const float*)d_in[15];

    const int NR = Bn*Tn;                            // 2048 rows
    float* giA = (float*)d_ws;                       // [pos][b][384] fp32, P-permuted, r/z pre-scaled
    float* giB = giA + (size_t)NR*G3;
    float* woE = giB + (size_t)NR*G3;                // [pos][b][128] fp32
    float* sW  = woE + (size_t)NR*HH;                // [b][i][k] fp32
    float* qW  = sW + (size_t)NR*Tn;
    ushort* wcv = (ushort*)(qW + (size_t)NR*Tn);     // bf16: Wemb|Wiha|Wihb
    ushort* wembB = wcv;                             // 131072
    ushort* wihaB = wcv + 131072;                    // 49152
    ushort* wihbB = wcv + 180224;                    // 49152

    k_cvt<<<dim3(112), 256, 0, stream>>>(Wemb, Wih_a, Wih_b, wcv);
    k_embgi<<<dim3(256), 512, 0, stream>>>(x, wembB, wihaB, wihbB,
                                           bih_a, bhh_a, bih_b, bhh_b, Wo,
                                           giA, giB, woE);
    k_gru<<<dim3(256), 1024, 0, stream>>>(Whh_a, bhh_a, Wa, ba,
                                          Whh_b, bhh_b, Wb, bb,
                                          giA, giB, woE, sW, qW);
    k_out<<<dim3(NR/4), 256, 0, stream>>>(sW, qW, bo, (float*)d_out);
}